// Round 3
// baseline (1483.752 us; speedup 1.0000x reference)
//
#include <hip/hip_runtime.h>
#include <hip/hip_cooperative_groups.h>

namespace cg = cooperative_groups;

#define IN_DIM 128
#define OUT_DIM 64

// broadcast lane l's value of v to all lanes via v_readlane (VALU/SALU path,
// keeps the DS pipe free for the W reads)
__device__ __forceinline__ float rdlane(float v, int l) {
    return __int_as_float(__builtin_amdgcn_readlane(__float_as_int(v), l));
}

// ---------------------------------------------------------------------------
// xw = x @ W.  8 rows per wave, lane = output column.  W in LDS k-major:
// wl[k*64+lane] is stride-1 per lane -> 2-way bank alias (free, m136).
// Per k: 1 ds_read_b32 + 8 readlane + 8 fma for 8 rows.
// ---------------------------------------------------------------------------
__global__ __launch_bounds__(256) void gemm_xw(const float* __restrict__ x,
                                               const float* __restrict__ w,
                                               float* __restrict__ xw, int N) {
    __shared__ float wl[IN_DIM * OUT_DIM];   // 32 KB
    {
        const float4* w4 = (const float4*)w;
        float4* wl4 = (float4*)wl;
        for (int i = threadIdx.x; i < IN_DIM * OUT_DIM / 4; i += 256)
            wl4[i] = w4[i];
    }
    __syncthreads();

    const int lane = threadIdx.x & 63;
    const int gw = (blockIdx.x * 256 + (int)threadIdx.x) >> 6;
    const int r0 = gw * 8;
    if (r0 >= N) return;

    float xr[8][2];
#pragma unroll
    for (int r = 0; r < 8; ++r) {
        int row = r0 + r; if (row >= N) row = N - 1;
        const float* xp = x + (size_t)row * IN_DIM;
        xr[r][0] = xp[lane];
        xr[r][1] = xp[64 + lane];
    }

    float acc[8] = {0.f, 0.f, 0.f, 0.f, 0.f, 0.f, 0.f, 0.f};
#pragma unroll
    for (int half = 0; half < 2; ++half) {
#pragma unroll
        for (int k = 0; k < 64; ++k) {
            float wv = wl[(half * 64 + k) * OUT_DIM + lane];
#pragma unroll
            for (int r = 0; r < 8; ++r)
                acc[r] = fmaf(rdlane(xr[r][half], k), wv, acc[r]);
        }
    }
#pragma unroll
    for (int r = 0; r < 8; ++r)
        if (r0 + r < N) xw[(size_t)(r0 + r) * OUT_DIM + lane] = acc[r];
}

// ---------------------------------------------------------------------------
// Cooperative fused aggregation: zero -> histogram -> scan -> fill -> pull.
// One dispatch; grid.sync() (device-scope fence, cross-XCD safe) between
// phases. 1 KB LDS, __launch_bounds__(256,8) caps VGPR at 64 so 8 blocks/CU
// co-reside (grid sized via occupancy query at launch).
// ---------------------------------------------------------------------------
__global__ __launch_bounds__(256, 8) void gcn_agg(
        const int* __restrict__ arow, const int* __restrict__ acol,
        const float* __restrict__ aval, const float* __restrict__ xw,
        int* cur, int* offs, int* bsum, float2* payload,
        float* __restrict__ out, int N, int E, int nchunks) {
    cg::grid_group grid = cg::this_grid();
    const int t = threadIdx.x;
    const int tid = blockIdx.x * 256 + t;
    const int nthreads = gridDim.x * 256;
    __shared__ int tmp[256];

    // phase 0: zero histogram/cursor array (d_ws is poisoned 0xAA each call)
    for (int i = tid; i < N; i += nthreads) cur[i] = 0;
    grid.sync();

    // phase 1: per-row degree histogram (int atomics on 200 KB, L2-resident)
    for (int e = tid; e < E; e += nthreads) atomicAdd(&cur[arow[e]], 1);
    grid.sync();

    // phase 2a: per-256-chunk exclusive scan
    if (blockIdx.x < nchunks) {
        const int i = blockIdx.x * 256 + t;
        int v = (i < N) ? cur[i] : 0;
        tmp[t] = v; __syncthreads();
        int run = v;
        for (int s = 1; s < 256; s <<= 1) {
            int a = (t >= s) ? tmp[t - s] : 0; __syncthreads();
            run += a; tmp[t] = run; __syncthreads();
        }
        if (i < N) offs[i] = run - v;
        if (t == 255) bsum[blockIdx.x] = run;
    }
    grid.sync();

    // phase 2b: scan the (<=256) chunk sums, single block
    if (blockIdx.x == 0) {
        int v = (t < nchunks) ? bsum[t] : 0;
        tmp[t] = v; __syncthreads();
        int run = v;
        for (int s = 1; s < 256; s <<= 1) {
            int a = (t >= s) ? tmp[t - s] : 0; __syncthreads();
            run += a; tmp[t] = run; __syncthreads();
        }
        if (t < nchunks) bsum[t] = run - v;
    }
    grid.sync();

    // phase 2c: add chunk bases; init fill cursors
    for (int i = tid; i < N; i += nthreads) {
        int o = offs[i] + bsum[i >> 8];
        offs[i] = o;
        cur[i] = o;
    }
    if (tid == 0) offs[N] = E;
    grid.sync();

    // phase 3: counting-sort fill of (col,val) payload, grouped by row
    for (int e = tid; e < E; e += nthreads) {
        const int r = arow[e];
        const int pos = atomicAdd(&cur[r], 1);
        payload[pos] = make_float2(__int_as_float(acol[e]), aval[e]);
    }
    grid.sync();

    // phase 4: pull + fused ReLU.  Wave per row, lane = column.  4-edge ILP:
    // 4 independent payload loads, then 4 independent 256 B gathers, 2 accs.
    const int lane = t & 63;
    const int gw = tid >> 6;
    const int nw = nthreads >> 6;
    for (int r = gw; r < N; r += nw) {
        int j = offs[r];
        const int end = offs[r + 1];
        float a0 = 0.f, a1 = 0.f;
        for (; j + 4 <= end; j += 4) {
            float2 p0 = payload[j];
            float2 p1 = payload[j + 1];
            float2 p2 = payload[j + 2];
            float2 p3 = payload[j + 3];
            float g0 = xw[(size_t)__float_as_int(p0.x) * OUT_DIM + lane];
            float g1 = xw[(size_t)__float_as_int(p1.x) * OUT_DIM + lane];
            float g2 = xw[(size_t)__float_as_int(p2.x) * OUT_DIM + lane];
            float g3 = xw[(size_t)__float_as_int(p3.x) * OUT_DIM + lane];
            a0 = fmaf(p0.y, g0, a0); a1 = fmaf(p1.y, g1, a1);
            a0 = fmaf(p2.y, g2, a0); a1 = fmaf(p3.y, g3, a1);
        }
        for (; j < end; ++j) {
            float2 p = payload[j];
            a0 = fmaf(p.y, xw[(size_t)__float_as_int(p.x) * OUT_DIM + lane], a0);
        }
        const float s = a0 + a1;
        out[(size_t)r * OUT_DIM + lane] = s > 0.f ? s : 0.f;
    }
}

// ---------------------------------------------------------------------------
// Fallback path (ws too small / N too big for the scan): R1 atomic scatter.
// ---------------------------------------------------------------------------
__global__ __launch_bounds__(256) void scatter_edges(
        const int* __restrict__ arow, const int* __restrict__ acol,
        const float* __restrict__ aval, const float* __restrict__ xw,
        float* __restrict__ out, int E) {
    const int lane = threadIdx.x & 63;
    int gw = (blockIdx.x * 256 + (int)threadIdx.x) >> 6;
    const int nw = (gridDim.x * 256) >> 6;
    for (int e = gw; e < E; e += nw) {
        const float m = aval[e] * xw[(size_t)acol[e] * OUT_DIM + lane];
        atomicAdd(&out[(size_t)arow[e] * OUT_DIM + lane], m);
    }
}

__global__ __launch_bounds__(256) void relu_inplace(float* __restrict__ o, int n4) {
    float4* p = (float4*)o;
    int i = blockIdx.x * 256 + threadIdx.x;
    const int stride = gridDim.x * 256;
    for (; i < n4; i += stride) {
        float4 v = p[i];
        v.x = v.x > 0.f ? v.x : 0.f;
        v.y = v.y > 0.f ? v.y : 0.f;
        v.z = v.z > 0.f ? v.z : 0.f;
        v.w = v.w > 0.f ? v.w : 0.f;
        p[i] = v;
    }
}

static inline size_t align256(size_t x) { return (x + 255) & ~(size_t)255; }

extern "C" void kernel_launch(void* const* d_in, const int* in_sizes, int n_in,
                              void* d_out, int out_size, void* d_ws, size_t ws_size,
                              hipStream_t stream) {
    const float* x    = (const float*)d_in[0];
    const float* w    = (const float*)d_in[1];
    const int*   arow = (const int*)d_in[2];
    const int*   acol = (const int*)d_in[3];
    const float* aval = (const float*)d_in[4];
    float*       out  = (float*)d_out;

    const int N = in_sizes[0] / IN_DIM;   // 50000
    const int E = in_sizes[2];            // 800000
    const int nchunks = (N + 255) / 256;  // 196

    // ws layout
    char* ws = (char*)d_ws;
    const size_t szXW   = align256((size_t)N * OUT_DIM * sizeof(float));
    const size_t szOffs = align256((size_t)(N + 1) * sizeof(int));
    const size_t szCur  = align256((size_t)N * sizeof(int));
    const size_t szB    = 1024;
    const size_t szPay  = (size_t)E * sizeof(float2);
    const size_t need   = szXW + szOffs + szCur + szB + szPay;

    float*  xw      = (float*)ws;
    int*    offs    = (int*)(ws + szXW);
    int*    cur     = (int*)(ws + szXW + szOffs);
    int*    bsum    = (int*)(ws + szXW + szOffs + szCur);
    float2* payload = (float2*)(ws + szXW + szOffs + szCur + szB);

    const int gemm_blocks = (N + 31) / 32;   // 8 rows/wave, 4 waves/block
    gemm_xw<<<gemm_blocks, 256, 0, stream>>>(x, w, xw, N);

    if (ws_size >= need && nchunks <= 256) {
        // size cooperative grid to guaranteed co-residency
        int dev = 0; hipGetDevice(&dev);
        int cus = 256;
        hipDeviceGetAttribute(&cus, hipDeviceAttributeMultiprocessorCount, dev);
        int maxBlk = 0;
        hipOccupancyMaxActiveBlocksPerMultiprocessor(&maxBlk, gcn_agg, 256, 0);
        if (maxBlk < 1) maxBlk = 1;
        long long g = (long long)cus * maxBlk;
        int grid = (g > 2048) ? 2048 : (int)g;
        if (grid < 64) grid = 64;

        void* args[] = {(void*)&arow, (void*)&acol, (void*)&aval, (void*)&xw,
                        (void*)&cur, (void*)&offs, (void*)&bsum, (void*)&payload,
                        (void*)&out, (void*)&N, (void*)&E, (void*)&nchunks};
        hipLaunchCooperativeKernel(gcn_agg, dim3(grid), dim3(256), args, 0, stream);
    } else {
        hipMemsetAsync(d_out, 0, (size_t)out_size * sizeof(float), stream);
        scatter_edges<<<4096, 256, 0, stream>>>(arow, acol, aval, xw, out, E);
        relu_inplace<<<2048, 256, 0, stream>>>(out, out_size / 4);
    }
}

// Round 4
// 231.939 us; speedup vs baseline: 6.3972x; 6.3972x over previous
//
#include <hip/hip_runtime.h>

#define IN_DIM 128
#define OUT_DIM 64
#define BUCKET 48   // fixed per-row payload stride; overflow handled correctly

// broadcast lane l's value of v to all lanes via v_readlane
__device__ __forceinline__ float rdlane(float v, int l) {
    return __int_as_float(__builtin_amdgcn_readlane(__float_as_int(v), l));
}

// ---------------------------------------------------------------------------
// xw = x @ W.  8 rows/wave, lane = out column.  W in LDS k-major (stride-1
// lane access -> free 2-way bank alias).  Per k: 1 ds_read + 8 readlane + 8 fma.
// ---------------------------------------------------------------------------
__global__ __launch_bounds__(256) void gemm_xw(const float* __restrict__ x,
                                               const float* __restrict__ w,
                                               float* __restrict__ xw, int N) {
    __shared__ float wl[IN_DIM * OUT_DIM];   // 32 KB
    {
        const float4* w4 = (const float4*)w;
        float4* wl4 = (float4*)wl;
        for (int i = threadIdx.x; i < IN_DIM * OUT_DIM / 4; i += 256)
            wl4[i] = w4[i];
    }
    __syncthreads();

    const int lane = threadIdx.x & 63;
    const int gw = (blockIdx.x * 256 + (int)threadIdx.x) >> 6;
    const int r0 = gw * 8;
    if (r0 >= N) return;

    float xr[8][2];
#pragma unroll
    for (int r = 0; r < 8; ++r) {
        int row = r0 + r; if (row >= N) row = N - 1;
        const float* xp = x + (size_t)row * IN_DIM;
        xr[r][0] = xp[lane];
        xr[r][1] = xp[64 + lane];
    }

    float acc[8] = {0.f, 0.f, 0.f, 0.f, 0.f, 0.f, 0.f, 0.f};
#pragma unroll
    for (int half = 0; half < 2; ++half) {
#pragma unroll
        for (int k = 0; k < 64; ++k) {
            float wv = wl[(half * 64 + k) * OUT_DIM + lane];
#pragma unroll
            for (int r = 0; r < 8; ++r)
                acc[r] = fmaf(rdlane(xr[r][half], k), wv, acc[r]);
        }
    }
#pragma unroll
    for (int r = 0; r < 8; ++r)
        if (r0 + r < N) xw[(size_t)(r0 + r) * OUT_DIM + lane] = acc[r];
}

// ---------------------------------------------------------------------------
// Fixed-stride bucket fill: payload[row*BUCKET + pos] = (col, val).
// One pass over edges, no hist/scan.  Overflow (pos >= BUCKET, ~never for
// Poisson(16) degrees) falls back to fp32 atomics into the zeroed out[].
// ---------------------------------------------------------------------------
__global__ __launch_bounds__(256) void fill_buckets(
        const int* __restrict__ arow, const int* __restrict__ acol,
        const float* __restrict__ aval, const float* __restrict__ xw,
        int* __restrict__ cur, float2* __restrict__ payload,
        float* __restrict__ out, int E) {
    int i = blockIdx.x * 256 + threadIdx.x;
    const int stride = gridDim.x * 256;
    for (int e = i; e < E; e += stride) {
        const int r = arow[e];
        const int c = acol[e];
        const float v = aval[e];
        const int pos = atomicAdd(&cur[r], 1);
        if (pos < BUCKET) {
            payload[(size_t)r * BUCKET + pos] = make_float2(__int_as_float(c), v);
        } else {
            // correctness escape hatch for pathological degree; ~never taken
            const float* src = xw + (size_t)c * OUT_DIM;
            float* dst = out + (size_t)r * OUT_DIM;
            for (int k = 0; k < OUT_DIM; ++k) atomicAdd(&dst[k], v * src[k]);
        }
    }
}

// ---------------------------------------------------------------------------
// Pull + ReLU, bucket layout.  Wave per row, lane = column.  4-edge ILP:
// 4 independent payload loads then 4 independent 256 B gathers -> 4x MLP
// vs R2's serialized chain (which was latency-bound: 15% BW, 15% VALU).
// ---------------------------------------------------------------------------
__global__ __launch_bounds__(256) void pull_buckets(
        const int* __restrict__ cur, const float2* __restrict__ payload,
        const float* __restrict__ xw, float* __restrict__ out, int N) {
    const int lane = threadIdx.x & 63;
    const int r = (blockIdx.x * 256 + (int)threadIdx.x) >> 6;
    if (r >= N) return;
    int deg = cur[r];
    if (deg > BUCKET) deg = BUCKET;
    const float2* p = payload + (size_t)r * BUCKET;
    float a0 = 0.f, a1 = 0.f;
    int j = 0;
    for (; j + 4 <= deg; j += 4) {
        float2 p0 = p[j], p1 = p[j + 1], p2 = p[j + 2], p3 = p[j + 3];
        float g0 = xw[(size_t)__float_as_int(p0.x) * OUT_DIM + lane];
        float g1 = xw[(size_t)__float_as_int(p1.x) * OUT_DIM + lane];
        float g2 = xw[(size_t)__float_as_int(p2.x) * OUT_DIM + lane];
        float g3 = xw[(size_t)__float_as_int(p3.x) * OUT_DIM + lane];
        a0 = fmaf(p0.y, g0, a0); a1 = fmaf(p1.y, g1, a1);
        a0 = fmaf(p2.y, g2, a0); a1 = fmaf(p3.y, g3, a1);
    }
    for (; j < deg; ++j) {
        float2 pp = p[j];
        a0 = fmaf(pp.y, xw[(size_t)__float_as_int(pp.x) * OUT_DIM + lane], a0);
    }
    // out[] was zeroed; holds overflow contributions (~always 0)
    const float s = a0 + a1 + out[(size_t)r * OUT_DIM + lane];
    out[(size_t)r * OUT_DIM + lane] = s > 0.f ? s : 0.f;
}

// ---------------------------------------------------------------------------
// CSR fallback path (middle tier): hist -> 3-kernel scan -> fill -> pull.
// ---------------------------------------------------------------------------
__global__ __launch_bounds__(256) void hist_rows(const int* __restrict__ arow,
                                                 int* __restrict__ cnt, int E) {
    int i = blockIdx.x * 256 + threadIdx.x;
    const int stride = gridDim.x * 256;
    for (int e = i; e < E; e += stride) atomicAdd(&cnt[arow[e]], 1);
}

__global__ __launch_bounds__(256) void scan1(const int* __restrict__ cnt,
                                             int* __restrict__ offs,
                                             int* __restrict__ bsum, int n) {
    __shared__ int tmp[256];
    const int t = threadIdx.x;
    const int i = blockIdx.x * 256 + t;
    int v = (i < n) ? cnt[i] : 0;
    tmp[t] = v; __syncthreads();
    int run = v;
    for (int s = 1; s < 256; s <<= 1) {
        int a = (t >= s) ? tmp[t - s] : 0; __syncthreads();
        run += a; tmp[t] = run; __syncthreads();
    }
    if (i < n) offs[i] = run - v;
    if (t == 255) bsum[blockIdx.x] = run;
}

__global__ __launch_bounds__(256) void scan2(int* __restrict__ bsum, int nb) {
    __shared__ int tmp[256];
    const int t = threadIdx.x;
    int v = (t < nb) ? bsum[t] : 0;
    tmp[t] = v; __syncthreads();
    int run = v;
    for (int s = 1; s < 256; s <<= 1) {
        int a = (t >= s) ? tmp[t - s] : 0; __syncthreads();
        run += a; tmp[t] = run; __syncthreads();
    }
    if (t < nb) bsum[t] = run - v;
}

__global__ __launch_bounds__(256) void scan3(int* __restrict__ offs,
                                             int* __restrict__ cur,
                                             const int* __restrict__ bsum,
                                             int n, int E) {
    const int i = blockIdx.x * 256 + threadIdx.x;
    if (i < n) {
        int o = offs[i] + bsum[blockIdx.x];
        offs[i] = o;
        cur[i] = o;
    }
    if (i == 0) offs[n] = E;
}

__global__ __launch_bounds__(256) void fill_csr(const int* __restrict__ arow,
                                                const int* __restrict__ acol,
                                                const float* __restrict__ aval,
                                                int* __restrict__ cur,
                                                float2* __restrict__ payload, int E) {
    int i = blockIdx.x * 256 + threadIdx.x;
    const int stride = gridDim.x * 256;
    for (int e = i; e < E; e += stride) {
        const int pos = atomicAdd(&cur[arow[e]], 1);
        payload[pos] = make_float2(__int_as_float(acol[e]), aval[e]);
    }
}

__global__ __launch_bounds__(256) void pull_csr(const int* __restrict__ offs,
                                                const float2* __restrict__ payload,
                                                const float* __restrict__ xw,
                                                float* __restrict__ out, int N) {
    const int lane = threadIdx.x & 63;
    const int r = (blockIdx.x * 256 + (int)threadIdx.x) >> 6;
    if (r >= N) return;
    int j = offs[r];
    const int end = offs[r + 1];
    float a0 = 0.f, a1 = 0.f;
    for (; j + 4 <= end; j += 4) {
        float2 p0 = payload[j], p1 = payload[j + 1];
        float2 p2 = payload[j + 2], p3 = payload[j + 3];
        float g0 = xw[(size_t)__float_as_int(p0.x) * OUT_DIM + lane];
        float g1 = xw[(size_t)__float_as_int(p1.x) * OUT_DIM + lane];
        float g2 = xw[(size_t)__float_as_int(p2.x) * OUT_DIM + lane];
        float g3 = xw[(size_t)__float_as_int(p3.x) * OUT_DIM + lane];
        a0 = fmaf(p0.y, g0, a0); a1 = fmaf(p1.y, g1, a1);
        a0 = fmaf(p2.y, g2, a0); a1 = fmaf(p3.y, g3, a1);
    }
    for (; j < end; ++j) {
        float2 pp = payload[j];
        a0 = fmaf(pp.y, xw[(size_t)__float_as_int(pp.x) * OUT_DIM + lane], a0);
    }
    const float s = a0 + a1;
    out[(size_t)r * OUT_DIM + lane] = s > 0.f ? s : 0.f;
}

// ---------------------------------------------------------------------------
// Last-resort fallback: atomic scatter.
// ---------------------------------------------------------------------------
__global__ __launch_bounds__(256) void scatter_edges(
        const int* __restrict__ arow, const int* __restrict__ acol,
        const float* __restrict__ aval, const float* __restrict__ xw,
        float* __restrict__ out, int E) {
    const int lane = threadIdx.x & 63;
    int gw = (blockIdx.x * 256 + (int)threadIdx.x) >> 6;
    const int nw = (gridDim.x * 256) >> 6;
    for (int e = gw; e < E; e += nw) {
        const float m = aval[e] * xw[(size_t)acol[e] * OUT_DIM + lane];
        atomicAdd(&out[(size_t)arow[e] * OUT_DIM + lane], m);
    }
}

__global__ __launch_bounds__(256) void relu_inplace(float* __restrict__ o, int n4) {
    float4* p = (float4*)o;
    int i = blockIdx.x * 256 + threadIdx.x;
    const int stride = gridDim.x * 256;
    for (; i < n4; i += stride) {
        float4 v = p[i];
        v.x = v.x > 0.f ? v.x : 0.f;
        v.y = v.y > 0.f ? v.y : 0.f;
        v.z = v.z > 0.f ? v.z : 0.f;
        v.w = v.w > 0.f ? v.w : 0.f;
        p[i] = v;
    }
}

static inline size_t align256(size_t x) { return (x + 255) & ~(size_t)255; }

extern "C" void kernel_launch(void* const* d_in, const int* in_sizes, int n_in,
                              void* d_out, int out_size, void* d_ws, size_t ws_size,
                              hipStream_t stream) {
    const float* x    = (const float*)d_in[0];
    const float* w    = (const float*)d_in[1];
    const int*   arow = (const int*)d_in[2];
    const int*   acol = (const int*)d_in[3];
    const float* aval = (const float*)d_in[4];
    float*       out  = (float*)d_out;

    const int N = in_sizes[0] / IN_DIM;   // 50000
    const int E = in_sizes[2];            // 800000
    const int nchunks = (N + 255) / 256;

    char* ws = (char*)d_ws;
    const size_t szXW  = align256((size_t)N * OUT_DIM * sizeof(float));
    const size_t szCur = align256((size_t)N * sizeof(int));

    float* xw  = (float*)ws;
    int*   cur = (int*)(ws + szXW);

    const int gemm_blocks = (N + 31) / 32;   // 8 rows/wave, 4 waves/block
    gemm_xw<<<gemm_blocks, 256, 0, stream>>>(x, w, xw, N);

    // --- tier 1: fixed-stride buckets (no hist/scan), need ~32.3 MB ---
    const size_t szPayB = (size_t)N * BUCKET * sizeof(float2);
    const size_t needB  = szXW + szCur + szPayB;

    // --- tier 2: CSR counting sort, need ~19.7 MB ---
    const size_t szOffs = align256((size_t)(N + 1) * sizeof(int));
    const size_t szB    = 1024;
    const size_t szPayC = (size_t)E * sizeof(float2);
    const size_t needC  = szXW + szOffs + szCur + szB + szPayC;

    if (ws_size >= needB) {
        float2* payload = (float2*)(ws + szXW + szCur);
        hipMemsetAsync(cur, 0, (size_t)N * sizeof(int), stream);
        hipMemsetAsync(d_out, 0, (size_t)out_size * sizeof(float), stream);
        fill_buckets<<<1600, 256, 0, stream>>>(arow, acol, aval, xw, cur,
                                               payload, out, E);
        pull_buckets<<<(N + 3) / 4, 256, 0, stream>>>(cur, payload, xw, out, N);
    } else if (ws_size >= needC && nchunks <= 256) {
        int*    offs    = (int*)(ws + szXW + szCur);
        int*    cur2    = cur;
        int*    bsum    = (int*)(ws + szXW + szCur + szOffs);
        float2* payload = (float2*)(ws + szXW + szCur + szOffs + szB);
        hipMemsetAsync(cur2, 0, (size_t)N * sizeof(int), stream);
        hist_rows<<<800, 256, 0, stream>>>(arow, cur2, E);
        scan1<<<nchunks, 256, 0, stream>>>(cur2, offs, bsum, N);
        scan2<<<1, 256, 0, stream>>>(bsum, nchunks);
        scan3<<<nchunks, 256, 0, stream>>>(offs, cur2, bsum, N, E);
        fill_csr<<<800, 256, 0, stream>>>(arow, acol, aval, cur2, payload, E);
        pull_csr<<<(N + 3) / 4, 256, 0, stream>>>(offs, payload, xw, out, N);
    } else {
        hipMemsetAsync(d_out, 0, (size_t)out_size * sizeof(float), stream);
        scatter_edges<<<4096, 256, 0, stream>>>(arow, acol, aval, xw, out, E);
        relu_inplace<<<2048, 256, 0, stream>>>(out, out_size / 4);
    }
}

// Round 5
// 178.533 us; speedup vs baseline: 8.3108x; 1.2991x over previous
//
#include <hip/hip_runtime.h>

#define IN_DIM 128
#define OUT_DIM 64
#define BUCKET 48   // fixed per-row payload stride; overflow handled correctly
#define PADK 136    // LDS row stride (bf16 elems): 272 B, 16B-aligned frags,
                    // start-bank 4m%32 + 16B span -> 8 hits/bank (balanced)

typedef float f32x4 __attribute__((ext_vector_type(4)));
typedef short bf16x8 __attribute__((ext_vector_type(8)));

__device__ __forceinline__ unsigned short f2bf(float f) {   // RNE f32->bf16
    unsigned u = __float_as_uint(f);
    return (unsigned short)((u + 0x7FFFu + ((u >> 16) & 1u)) >> 16);
}
__device__ __forceinline__ float bf2f(unsigned short h) {
    return __uint_as_float((unsigned)h << 16);
}

// ---------------------------------------------------------------------------
// xw = x @ W via split-bf16 MFMA: x = xhi + xlo, W = whi + wlo (RNE splits),
// xw ~= xhi*whi + xhi*wlo + xlo*whi  (lo*lo ~ 2^-18 rel, dropped).
// 64 rows/block, wave w owns 16-row tile; 4 col-tiles of 16; K=128 = 4 steps.
// ---------------------------------------------------------------------------
__global__ __launch_bounds__(256) void gemm_xw_mfma(const float* __restrict__ x,
                                                    const float* __restrict__ w,
                                                    float* __restrict__ xw, int N) {
    __shared__ unsigned short Ahi[64 * PADK];   // 17 KB each, 68 KB total
    __shared__ unsigned short Alo[64 * PADK];
    __shared__ unsigned short Bhi[64 * PADK];   // W^T: [c][k], k-contiguous
    __shared__ unsigned short Blo[64 * PADK];

    const int t = threadIdx.x;
    const int r0 = blockIdx.x * 64;

    // --- stage W^T hi/lo: thread -> (c = t>>2, k-range (t&3)*32..+32) ---
    {
        const int c = t >> 2;
        const int kb = (t & 3) * 32;
        for (int k4 = 0; k4 < 32; k4 += 4) {
            ushort4 h, l;
            float v0 = w[(kb + k4 + 0) * OUT_DIM + c];
            float v1 = w[(kb + k4 + 1) * OUT_DIM + c];
            float v2 = w[(kb + k4 + 2) * OUT_DIM + c];
            float v3 = w[(kb + k4 + 3) * OUT_DIM + c];
            h.x = f2bf(v0); l.x = f2bf(v0 - bf2f(h.x));
            h.y = f2bf(v1); l.y = f2bf(v1 - bf2f(h.y));
            h.z = f2bf(v2); l.z = f2bf(v2 - bf2f(h.z));
            h.w = f2bf(v3); l.w = f2bf(v3 - bf2f(h.w));
            *(ushort4*)&Bhi[c * PADK + kb + k4] = h;
            *(ushort4*)&Blo[c * PADK + kb + k4] = l;
        }
    }
    // --- stage x rows hi/lo: flat float4 map, fully coalesced ---
    {
        const float4* x4 = (const float4*)x;
        for (int i = 0; i < 8; ++i) {
            const int f = i * 256 + t;        // float4 idx in 64x128 tile
            const int rr = f >> 5;            // tile row
            const int kk = (f & 31) * 4;      // k
            int row = r0 + rr; if (row >= N) row = N - 1;
            float4 v = x4[(size_t)row * (IN_DIM / 4) + (kk >> 2)];
            ushort4 h, l;
            h.x = f2bf(v.x); l.x = f2bf(v.x - bf2f(h.x));
            h.y = f2bf(v.y); l.y = f2bf(v.y - bf2f(h.y));
            h.z = f2bf(v.z); l.z = f2bf(v.z - bf2f(h.z));
            h.w = f2bf(v.w); l.w = f2bf(v.w - bf2f(h.w));
            *(ushort4*)&Ahi[rr * PADK + kk] = h;
            *(ushort4*)&Alo[rr * PADK + kk] = l;
        }
    }
    __syncthreads();

    const int lane = t & 63;
    const int wv = t >> 6;            // 16-row tile within block
    const int m = lane & 15;
    const int quad = lane >> 4;

    // A frags (reused across all 4 col-tiles): A[m][k=quad*8+j]
    bf16x8 ahi[4], alo[4];
#pragma unroll
    for (int ks = 0; ks < 4; ++ks) {
        const int off = (wv * 16 + m) * PADK + ks * 32 + quad * 8;
        ahi[ks] = *(const bf16x8*)&Ahi[off];
        alo[ks] = *(const bf16x8*)&Alo[off];
    }
#pragma unroll
    for (int ct = 0; ct < 4; ++ct) {
        f32x4 acc = {0.f, 0.f, 0.f, 0.f};
#pragma unroll
        for (int ks = 0; ks < 4; ++ks) {
            const int off = (ct * 16 + m) * PADK + ks * 32 + quad * 8;
            bf16x8 bh = *(const bf16x8*)&Bhi[off];   // B[k=quad*8+j][n=m]
            bf16x8 bl = *(const bf16x8*)&Blo[off];
            acc = __builtin_amdgcn_mfma_f32_16x16x32_bf16(alo[ks], bh, acc, 0, 0, 0);
            acc = __builtin_amdgcn_mfma_f32_16x16x32_bf16(ahi[ks], bl, acc, 0, 0, 0);
            acc = __builtin_amdgcn_mfma_f32_16x16x32_bf16(ahi[ks], bh, acc, 0, 0, 0);
        }
#pragma unroll
        for (int i = 0; i < 4; ++i) {               // D: row=quad*4+i, col=m
            const int row = r0 + wv * 16 + quad * 4 + i;
            if (row < N) xw[(size_t)row * OUT_DIM + ct * 16 + m] = acc[i];
        }
    }
}

// ---------------------------------------------------------------------------
// Fixed-stride bucket fill: payload[row*BUCKET + pos] = (col, val).
// Overflow (pos >= BUCKET, ~never for Poisson(16)) -> fp32 atomics into
// zeroed out[].
// ---------------------------------------------------------------------------
__global__ __launch_bounds__(256) void fill_buckets(
        const int* __restrict__ arow, const int* __restrict__ acol,
        const float* __restrict__ aval, const float* __restrict__ xw,
        int* __restrict__ cur, float2* __restrict__ payload,
        float* __restrict__ out, int E) {
    int i = blockIdx.x * 256 + threadIdx.x;
    const int stride = gridDim.x * 256;
    for (int e = i; e < E; e += stride) {
        const int r = arow[e];
        const int c = acol[e];
        const float v = aval[e];
        const int pos = atomicAdd(&cur[r], 1);
        if (pos < BUCKET) {
            payload[(size_t)r * BUCKET + pos] = make_float2(__int_as_float(c), v);
        } else {
            const float* src = xw + (size_t)c * OUT_DIM;
            float* dst = out + (size_t)r * OUT_DIM;
            for (int k = 0; k < OUT_DIM; ++k) atomicAdd(&dst[k], v * src[k]);
        }
    }
}

// ---------------------------------------------------------------------------
// Pull + ReLU, bucket layout.  Wave per row, lane = column, 4-edge ILP.
// ---------------------------------------------------------------------------
__global__ __launch_bounds__(256) void pull_buckets(
        const int* __restrict__ cur, const float2* __restrict__ payload,
        const float* __restrict__ xw, float* __restrict__ out, int N) {
    const int lane = threadIdx.x & 63;
    const int r = (blockIdx.x * 256 + (int)threadIdx.x) >> 6;
    if (r >= N) return;
    int deg = cur[r];
    if (deg > BUCKET) deg = BUCKET;
    const float2* p = payload + (size_t)r * BUCKET;
    float a0 = 0.f, a1 = 0.f;
    int j = 0;
    for (; j + 4 <= deg; j += 4) {
        float2 p0 = p[j], p1 = p[j + 1], p2 = p[j + 2], p3 = p[j + 3];
        float g0 = xw[(size_t)__float_as_int(p0.x) * OUT_DIM + lane];
        float g1 = xw[(size_t)__float_as_int(p1.x) * OUT_DIM + lane];
        float g2 = xw[(size_t)__float_as_int(p2.x) * OUT_DIM + lane];
        float g3 = xw[(size_t)__float_as_int(p3.x) * OUT_DIM + lane];
        a0 = fmaf(p0.y, g0, a0); a1 = fmaf(p1.y, g1, a1);
        a0 = fmaf(p2.y, g2, a0); a1 = fmaf(p3.y, g3, a1);
    }
    for (; j < deg; ++j) {
        float2 pp = p[j];
        a0 = fmaf(pp.y, xw[(size_t)__float_as_int(pp.x) * OUT_DIM + lane], a0);
    }
    const float s = a0 + a1 + out[(size_t)r * OUT_DIM + lane];
    out[(size_t)r * OUT_DIM + lane] = s > 0.f ? s : 0.f;
}

// ---------------------------------------------------------------------------
// CSR fallback tier: hist -> 3-kernel scan -> fill -> pull.
// ---------------------------------------------------------------------------
__global__ __launch_bounds__(256) void hist_rows(const int* __restrict__ arow,
                                                 int* __restrict__ cnt, int E) {
    int i = blockIdx.x * 256 + threadIdx.x;
    const int stride = gridDim.x * 256;
    for (int e = i; e < E; e += stride) atomicAdd(&cnt[arow[e]], 1);
}

__global__ __launch_bounds__(256) void scan1(const int* __restrict__ cnt,
                                             int* __restrict__ offs,
                                             int* __restrict__ bsum, int n) {
    __shared__ int tmp[256];
    const int t = threadIdx.x;
    const int i = blockIdx.x * 256 + t;
    int v = (i < n) ? cnt[i] : 0;
    tmp[t] = v; __syncthreads();
    int run = v;
    for (int s = 1; s < 256; s <<= 1) {
        int a = (t >= s) ? tmp[t - s] : 0; __syncthreads();
        run += a; tmp[t] = run; __syncthreads();
    }
    if (i < n) offs[i] = run - v;
    if (t == 255) bsum[blockIdx.x] = run;
}

__global__ __launch_bounds__(256) void scan2(int* __restrict__ bsum, int nb) {
    __shared__ int tmp[256];
    const int t = threadIdx.x;
    int v = (t < nb) ? bsum[t] : 0;
    tmp[t] = v; __syncthreads();
    int run = v;
    for (int s = 1; s < 256; s <<= 1) {
        int a = (t >= s) ? tmp[t - s] : 0; __syncthreads();
        run += a; tmp[t] = run; __syncthreads();
    }
    if (t < nb) bsum[t] = run - v;
}

__global__ __launch_bounds__(256) void scan3(int* __restrict__ offs,
                                             int* __restrict__ cur,
                                             const int* __restrict__ bsum,
                                             int n, int E) {
    const int i = blockIdx.x * 256 + threadIdx.x;
    if (i < n) {
        int o = offs[i] + bsum[blockIdx.x];
        offs[i] = o;
        cur[i] = o;
    }
    if (i == 0) offs[n] = E;
}

__global__ __launch_bounds__(256) void fill_csr(const int* __restrict__ arow,
                                                const int* __restrict__ acol,
                                                const float* __restrict__ aval,
                                                int* __restrict__ cur,
                                                float2* __restrict__ payload, int E) {
    int i = blockIdx.x * 256 + threadIdx.x;
    const int stride = gridDim.x * 256;
    for (int e = i; e < E; e += stride) {
        const int pos = atomicAdd(&cur[arow[e]], 1);
        payload[pos] = make_float2(__int_as_float(acol[e]), aval[e]);
    }
}

__global__ __launch_bounds__(256) void pull_csr(const int* __restrict__ offs,
                                                const float2* __restrict__ payload,
                                                const float* __restrict__ xw,
                                                float* __restrict__ out, int N) {
    const int lane = threadIdx.x & 63;
    const int r = (blockIdx.x * 256 + (int)threadIdx.x) >> 6;
    if (r >= N) return;
    int j = offs[r];
    const int end = offs[r + 1];
    float a0 = 0.f, a1 = 0.f;
    for (; j + 4 <= end; j += 4) {
        float2 p0 = payload[j], p1 = payload[j + 1];
        float2 p2 = payload[j + 2], p3 = payload[j + 3];
        float g0 = xw[(size_t)__float_as_int(p0.x) * OUT_DIM + lane];
        float g1 = xw[(size_t)__float_as_int(p1.x) * OUT_DIM + lane];
        float g2 = xw[(size_t)__float_as_int(p2.x) * OUT_DIM + lane];
        float g3 = xw[(size_t)__float_as_int(p3.x) * OUT_DIM + lane];
        a0 = fmaf(p0.y, g0, a0); a1 = fmaf(p1.y, g1, a1);
        a0 = fmaf(p2.y, g2, a0); a1 = fmaf(p3.y, g3, a1);
    }
    for (; j < end; ++j) {
        float2 pp = payload[j];
        a0 = fmaf(pp.y, xw[(size_t)__float_as_int(pp.x) * OUT_DIM + lane], a0);
    }
    const float s = a0 + a1;
    out[(size_t)r * OUT_DIM + lane] = s > 0.f ? s : 0.f;
}

// ---------------------------------------------------------------------------
// Last-resort fallback: atomic scatter.
// ---------------------------------------------------------------------------
__global__ __launch_bounds__(256) void scatter_edges(
        const int* __restrict__ arow, const int* __restrict__ acol,
        const float* __restrict__ aval, const float* __restrict__ xw,
        float* __restrict__ out, int E) {
    const int lane = threadIdx.x & 63;
    int gw = (blockIdx.x * 256 + (int)threadIdx.x) >> 6;
    const int nw = (gridDim.x * 256) >> 6;
    for (int e = gw; e < E; e += nw) {
        const float m = aval[e] * xw[(size_t)acol[e] * OUT_DIM + lane];
        atomicAdd(&out[(size_t)arow[e] * OUT_DIM + lane], m);
    }
}

__global__ __launch_bounds__(256) void relu_inplace(float* __restrict__ o, int n4) {
    float4* p = (float4*)o;
    int i = blockIdx.x * 256 + threadIdx.x;
    const int stride = gridDim.x * 256;
    for (; i < n4; i += stride) {
        float4 v = p[i];
        v.x = v.x > 0.f ? v.x : 0.f;
        v.y = v.y > 0.f ? v.y : 0.f;
        v.z = v.z > 0.f ? v.z : 0.f;
        v.w = v.w > 0.f ? v.w : 0.f;
        p[i] = v;
    }
}

static inline size_t align256(size_t x) { return (x + 255) & ~(size_t)255; }

extern "C" void kernel_launch(void* const* d_in, const int* in_sizes, int n_in,
                              void* d_out, int out_size, void* d_ws, size_t ws_size,
                              hipStream_t stream) {
    const float* x    = (const float*)d_in[0];
    const float* w    = (const float*)d_in[1];
    const int*   arow = (const int*)d_in[2];
    const int*   acol = (const int*)d_in[3];
    const float* aval = (const float*)d_in[4];
    float*       out  = (float*)d_out;

    const int N = in_sizes[0] / IN_DIM;   // 50000
    const int E = in_sizes[2];            // 800000
    const int nchunks = (N + 255) / 256;

    char* ws = (char*)d_ws;
    const size_t szXW  = align256((size_t)N * OUT_DIM * sizeof(float));
    const size_t szCur = align256((size_t)N * sizeof(int));

    float* xw  = (float*)ws;
    int*   cur = (int*)(ws + szXW);

    gemm_xw_mfma<<<(N + 63) / 64, 256, 0, stream>>>(x, w, xw, N);

    // --- tier 1: fixed-stride buckets ---
    const size_t szPayB = (size_t)N * BUCKET * sizeof(float2);
    const size_t needB  = szXW + szCur + szPayB;

    // --- tier 2: CSR counting sort ---
    const size_t szOffs = align256((size_t)(N + 1) * sizeof(int));
    const size_t szB    = 1024;
    const size_t szPayC = (size_t)E * sizeof(float2);
    const size_t needC  = szXW + szOffs + szCur + szB + szPayC;

    if (ws_size >= needB) {
        float2* payload = (float2*)(ws + szXW + szCur);
        hipMemsetAsync(cur, 0, (size_t)N * sizeof(int), stream);
        hipMemsetAsync(d_out, 0, (size_t)out_size * sizeof(float), stream);
        fill_buckets<<<1600, 256, 0, stream>>>(arow, acol, aval, xw, cur,
                                               payload, out, E);
        pull_buckets<<<(N + 3) / 4, 256, 0, stream>>>(cur, payload, xw, out, N);
    } else if (ws_size >= needC && nchunks <= 256) {
        int*    offs    = (int*)(ws + szXW + szCur);
        int*    bsum    = (int*)(ws + szXW + szCur + szOffs);
        float2* payload = (float2*)(ws + szXW + szCur + szOffs + szB);
        hipMemsetAsync(cur, 0, (size_t)N * sizeof(int), stream);
        hist_rows<<<800, 256, 0, stream>>>(arow, cur, E);
        scan1<<<nchunks, 256, 0, stream>>>(cur, offs, bsum, N);
        scan2<<<1, 256, 0, stream>>>(bsum, nchunks);
        scan3<<<nchunks, 256, 0, stream>>>(offs, cur, bsum, N, E);
        fill_csr<<<800, 256, 0, stream>>>(arow, acol, aval, cur, payload, E);
        pull_csr<<<(N + 3) / 4, 256, 0, stream>>>(offs, payload, xw, out, N);
    } else {
        hipMemsetAsync(d_out, 0, (size_t)out_size * sizeof(float), stream);
        scatter_edges<<<4096, 256, 0, stream>>>(arow, acol, aval, xw, out, E);
        relu_inplace<<<2048, 256, 0, stream>>>(out, out_size / 4);
    }
}

// Round 6
// 169.733 us; speedup vs baseline: 8.7417x; 1.0518x over previous
//
#include <hip/hip_runtime.h>

#define IN_DIM 128
#define OUT_DIM 64
#define BUCKET 48   // fixed per-row payload stride
#define PADK 136    // gemm LDS row stride (bf16 elems)

typedef float f32x4 __attribute__((ext_vector_type(4)));
typedef short bf16x8 __attribute__((ext_vector_type(8)));

__device__ __forceinline__ unsigned short f2bf(float f) {   // RNE f32->bf16
    unsigned u = __float_as_uint(f);
    return (unsigned short)((u + 0x7FFFu + ((u >> 16) & 1u)) >> 16);
}
__device__ __forceinline__ float bf2f(unsigned short h) {
    return __uint_as_float((unsigned)h << 16);
}
// pack (col:u16 low | val:bf16 high) into 4 B
__device__ __forceinline__ unsigned packcv(int c, float v) {
    return (unsigned)(c & 0xFFFF) | ((unsigned)f2bf(v) << 16);
}

// ---------------------------------------------------------------------------
// xw = x @ W via split-bf16 MFMA (hi*hi + hi*lo + lo*hi), 64 rows/block.
// ---------------------------------------------------------------------------
__global__ __launch_bounds__(256) void gemm_xw_mfma(const float* __restrict__ x,
                                                    const float* __restrict__ w,
                                                    float* __restrict__ xw, int N) {
    __shared__ unsigned short Ahi[64 * PADK];
    __shared__ unsigned short Alo[64 * PADK];
    __shared__ unsigned short Bhi[64 * PADK];   // W^T: [c][k]
    __shared__ unsigned short Blo[64 * PADK];

    const int t = threadIdx.x;
    const int r0 = blockIdx.x * 64;

    {   // stage W^T hi/lo
        const int c = t >> 2;
        const int kb = (t & 3) * 32;
        for (int k4 = 0; k4 < 32; k4 += 4) {
            ushort4 h, l;
            float v0 = w[(kb + k4 + 0) * OUT_DIM + c];
            float v1 = w[(kb + k4 + 1) * OUT_DIM + c];
            float v2 = w[(kb + k4 + 2) * OUT_DIM + c];
            float v3 = w[(kb + k4 + 3) * OUT_DIM + c];
            h.x = f2bf(v0); l.x = f2bf(v0 - bf2f(h.x));
            h.y = f2bf(v1); l.y = f2bf(v1 - bf2f(h.y));
            h.z = f2bf(v2); l.z = f2bf(v2 - bf2f(h.z));
            h.w = f2bf(v3); l.w = f2bf(v3 - bf2f(h.w));
            *(ushort4*)&Bhi[c * PADK + kb + k4] = h;
            *(ushort4*)&Blo[c * PADK + kb + k4] = l;
        }
    }
    {   // stage x rows hi/lo
        const float4* x4 = (const float4*)x;
        for (int i = 0; i < 8; ++i) {
            const int f = i * 256 + t;
            const int rr = f >> 5;
            const int kk = (f & 31) * 4;
            int row = r0 + rr; if (row >= N) row = N - 1;
            float4 v = x4[(size_t)row * (IN_DIM / 4) + (kk >> 2)];
            ushort4 h, l;
            h.x = f2bf(v.x); l.x = f2bf(v.x - bf2f(h.x));
            h.y = f2bf(v.y); l.y = f2bf(v.y - bf2f(h.y));
            h.z = f2bf(v.z); l.z = f2bf(v.z - bf2f(h.z));
            h.w = f2bf(v.w); l.w = f2bf(v.w - bf2f(h.w));
            *(ushort4*)&Ahi[rr * PADK + kk] = h;
            *(ushort4*)&Alo[rr * PADK + kk] = l;
        }
    }
    __syncthreads();

    const int lane = t & 63;
    const int wv = t >> 6;
    const int m = lane & 15;
    const int quad = lane >> 4;

    bf16x8 ahi[4], alo[4];
#pragma unroll
    for (int ks = 0; ks < 4; ++ks) {
        const int off = (wv * 16 + m) * PADK + ks * 32 + quad * 8;
        ahi[ks] = *(const bf16x8*)&Ahi[off];
        alo[ks] = *(const bf16x8*)&Alo[off];
    }
#pragma unroll
    for (int ct = 0; ct < 4; ++ct) {
        f32x4 acc = {0.f, 0.f, 0.f, 0.f};
#pragma unroll
        for (int ks = 0; ks < 4; ++ks) {
            const int off = (ct * 16 + m) * PADK + ks * 32 + quad * 8;
            bf16x8 bh = *(const bf16x8*)&Bhi[off];
            bf16x8 bl = *(const bf16x8*)&Blo[off];
            acc = __builtin_amdgcn_mfma_f32_16x16x32_bf16(alo[ks], bh, acc, 0, 0, 0);
            acc = __builtin_amdgcn_mfma_f32_16x16x32_bf16(ahi[ks], bl, acc, 0, 0, 0);
            acc = __builtin_amdgcn_mfma_f32_16x16x32_bf16(ahi[ks], bh, acc, 0, 0, 0);
        }
#pragma unroll
        for (int i = 0; i < 4; ++i) {
            const int row = r0 + wv * 16 + quad * 4 + i;
            if (row < N) xw[(size_t)row * OUT_DIM + ct * 16 + m] = acc[i];
        }
    }
}

// ---------------------------------------------------------------------------
// Bucket fill, 4-edge ILP: int4/float4 edge loads -> 4 independent atomics
// -> 4 independent packed 4 B stores.  Overflow (pos >= BUCKET): store
// nothing; pull detects cur[r] > BUCKET and re-scans the edge list (correct,
// ~never taken for Poisson(16) degrees).  No xw/out dependency.
// ---------------------------------------------------------------------------
__global__ __launch_bounds__(256) void fill_buckets(
        const int* __restrict__ arow, const int* __restrict__ acol,
        const float* __restrict__ aval, int* __restrict__ cur,
        unsigned* __restrict__ payload, int E) {
    const int nt = gridDim.x * 256;
    const int tid = blockIdx.x * 256 + threadIdx.x;
    const int E4 = E >> 2;
    const int4*   ar4 = (const int4*)arow;
    const int4*   ac4 = (const int4*)acol;
    const float4* av4 = (const float4*)aval;
    for (int q = tid; q < E4; q += nt) {
        int4   r = ar4[q];
        int4   c = ac4[q];
        float4 v = av4[q];
        int p0 = atomicAdd(&cur[r.x], 1);
        int p1 = atomicAdd(&cur[r.y], 1);
        int p2 = atomicAdd(&cur[r.z], 1);
        int p3 = atomicAdd(&cur[r.w], 1);
        if (p0 < BUCKET) payload[(size_t)r.x * BUCKET + p0] = packcv(c.x, v.x);
        if (p1 < BUCKET) payload[(size_t)r.y * BUCKET + p1] = packcv(c.y, v.y);
        if (p2 < BUCKET) payload[(size_t)r.z * BUCKET + p2] = packcv(c.z, v.z);
        if (p3 < BUCKET) payload[(size_t)r.w * BUCKET + p3] = packcv(c.w, v.w);
    }
    for (int e = E4 * 4 + tid; e < E; e += nt) {   // tail (E % 4)
        const int pos = atomicAdd(&cur[arow[e]], 1);
        if (pos < BUCKET)
            payload[(size_t)arow[e] * BUCKET + pos] = packcv(acol[e], aval[e]);
    }
}

// ---------------------------------------------------------------------------
// Pull + ReLU.  Wave per row, lane = column, 8-edge ILP on 4 B payload.
// Overflow rows (deg_raw > BUCKET) recompute from the raw edge list.
// ---------------------------------------------------------------------------
__global__ __launch_bounds__(256) void pull_buckets(
        const int* __restrict__ cur, const unsigned* __restrict__ payload,
        const float* __restrict__ xw, float* __restrict__ out, int N,
        const int* __restrict__ arow, const int* __restrict__ acol,
        const float* __restrict__ aval, int E) {
    const int lane = threadIdx.x & 63;
    const int r = (blockIdx.x * 256 + (int)threadIdx.x) >> 6;
    if (r >= N) return;
    const int deg_raw = cur[r];
    float a0 = 0.f, a1 = 0.f;
    if (deg_raw <= BUCKET) {
        const unsigned* p = payload + (size_t)r * BUCKET;
        int j = 0;
        for (; j + 8 <= deg_raw; j += 8) {
            unsigned w0 = p[j], w1 = p[j+1], w2 = p[j+2], w3 = p[j+3];
            unsigned w4 = p[j+4], w5 = p[j+5], w6 = p[j+6], w7 = p[j+7];
            float g0 = xw[(size_t)(w0 & 0xFFFF) * OUT_DIM + lane];
            float g1 = xw[(size_t)(w1 & 0xFFFF) * OUT_DIM + lane];
            float g2 = xw[(size_t)(w2 & 0xFFFF) * OUT_DIM + lane];
            float g3 = xw[(size_t)(w3 & 0xFFFF) * OUT_DIM + lane];
            float g4 = xw[(size_t)(w4 & 0xFFFF) * OUT_DIM + lane];
            float g5 = xw[(size_t)(w5 & 0xFFFF) * OUT_DIM + lane];
            float g6 = xw[(size_t)(w6 & 0xFFFF) * OUT_DIM + lane];
            float g7 = xw[(size_t)(w7 & 0xFFFF) * OUT_DIM + lane];
            a0 = fmaf(__uint_as_float(w0 & 0xFFFF0000u), g0, a0);
            a1 = fmaf(__uint_as_float(w1 & 0xFFFF0000u), g1, a1);
            a0 = fmaf(__uint_as_float(w2 & 0xFFFF0000u), g2, a0);
            a1 = fmaf(__uint_as_float(w3 & 0xFFFF0000u), g3, a1);
            a0 = fmaf(__uint_as_float(w4 & 0xFFFF0000u), g4, a0);
            a1 = fmaf(__uint_as_float(w5 & 0xFFFF0000u), g5, a1);
            a0 = fmaf(__uint_as_float(w6 & 0xFFFF0000u), g6, a0);
            a1 = fmaf(__uint_as_float(w7 & 0xFFFF0000u), g7, a1);
        }
        for (; j < deg_raw; ++j) {
            unsigned wj = p[j];
            a0 = fmaf(__uint_as_float(wj & 0xFFFF0000u),
                      xw[(size_t)(wj & 0xFFFF) * OUT_DIM + lane], a0);
        }
    } else {
        // correctness escape hatch: rescan the raw edge list (~never taken)
        for (int e = 0; e < E; ++e)
            if (arow[e] == r)
                a0 = fmaf(aval[e], xw[(size_t)acol[e] * OUT_DIM + lane], a0);
    }
    const float s = a0 + a1;
    out[(size_t)r * OUT_DIM + lane] = s > 0.f ? s : 0.f;
}

// ---------------------------------------------------------------------------
// CSR fallback tier (8 B payload, no N<=65536 requirement).
// ---------------------------------------------------------------------------
__global__ __launch_bounds__(256) void hist_rows(const int* __restrict__ arow,
                                                 int* __restrict__ cnt, int E) {
    int i = blockIdx.x * 256 + threadIdx.x;
    const int stride = gridDim.x * 256;
    for (int e = i; e < E; e += stride) atomicAdd(&cnt[arow[e]], 1);
}

__global__ __launch_bounds__(256) void scan1(const int* __restrict__ cnt,
                                             int* __restrict__ offs,
                                             int* __restrict__ bsum, int n) {
    __shared__ int tmp[256];
    const int t = threadIdx.x;
    const int i = blockIdx.x * 256 + t;
    int v = (i < n) ? cnt[i] : 0;
    tmp[t] = v; __syncthreads();
    int run = v;
    for (int s = 1; s < 256; s <<= 1) {
        int a = (t >= s) ? tmp[t - s] : 0; __syncthreads();
        run += a; tmp[t] = run; __syncthreads();
    }
    if (i < n) offs[i] = run - v;
    if (t == 255) bsum[blockIdx.x] = run;
}

__global__ __launch_bounds__(256) void scan2(int* __restrict__ bsum, int nb) {
    __shared__ int tmp[256];
    const int t = threadIdx.x;
    int v = (t < nb) ? bsum[t] : 0;
    tmp[t] = v; __syncthreads();
    int run = v;
    for (int s = 1; s < 256; s <<= 1) {
        int a = (t >= s) ? tmp[t - s] : 0; __syncthreads();
        run += a; tmp[t] = run; __syncthreads();
    }
    if (t < nb) bsum[t] = run - v;
}

__global__ __launch_bounds__(256) void scan3(int* __restrict__ offs,
                                             int* __restrict__ cur,
                                             const int* __restrict__ bsum,
                                             int n, int E) {
    const int i = blockIdx.x * 256 + threadIdx.x;
    if (i < n) {
        int o = offs[i] + bsum[blockIdx.x];
        offs[i] = o;
        cur[i] = o;
    }
    if (i == 0) offs[n] = E;
}

__global__ __launch_bounds__(256) void fill_csr(const int* __restrict__ arow,
                                                const int* __restrict__ acol,
                                                const float* __restrict__ aval,
                                                int* __restrict__ cur,
                                                float2* __restrict__ payload, int E) {
    int i = blockIdx.x * 256 + threadIdx.x;
    const int stride = gridDim.x * 256;
    for (int e = i; e < E; e += stride) {
        const int pos = atomicAdd(&cur[arow[e]], 1);
        payload[pos] = make_float2(__int_as_float(acol[e]), aval[e]);
    }
}

__global__ __launch_bounds__(256) void pull_csr(const int* __restrict__ offs,
                                                const float2* __restrict__ payload,
                                                const float* __restrict__ xw,
                                                float* __restrict__ out, int N) {
    const int lane = threadIdx.x & 63;
    const int r = (blockIdx.x * 256 + (int)threadIdx.x) >> 6;
    if (r >= N) return;
    int j = offs[r];
    const int end = offs[r + 1];
    float a0 = 0.f, a1 = 0.f;
    for (; j + 4 <= end; j += 4) {
        float2 p0 = payload[j], p1 = payload[j + 1];
        float2 p2 = payload[j + 2], p3 = payload[j + 3];
        float g0 = xw[(size_t)__float_as_int(p0.x) * OUT_DIM + lane];
        float g1 = xw[(size_t)__float_as_int(p1.x) * OUT_DIM + lane];
        float g2 = xw[(size_t)__float_as_int(p2.x) * OUT_DIM + lane];
        float g3 = xw[(size_t)__float_as_int(p3.x) * OUT_DIM + lane];
        a0 = fmaf(p0.y, g0, a0); a1 = fmaf(p1.y, g1, a1);
        a0 = fmaf(p2.y, g2, a0); a1 = fmaf(p3.y, g3, a1);
    }
    for (; j < end; ++j) {
        float2 pp = payload[j];
        a0 = fmaf(pp.y, xw[(size_t)__float_as_int(pp.x) * OUT_DIM + lane], a0);
    }
    const float s = a0 + a1;
    out[(size_t)r * OUT_DIM + lane] = s > 0.f ? s : 0.f;
}

// ---------------------------------------------------------------------------
// Last-resort fallback: atomic scatter.
// ---------------------------------------------------------------------------
__global__ __launch_bounds__(256) void scatter_edges(
        const int* __restrict__ arow, const int* __restrict__ acol,
        const float* __restrict__ aval, const float* __restrict__ xw,
        float* __restrict__ out, int E) {
    const int lane = threadIdx.x & 63;
    int gw = (blockIdx.x * 256 + (int)threadIdx.x) >> 6;
    const int nw = (gridDim.x * 256) >> 6;
    for (int e = gw; e < E; e += nw) {
        const float m = aval[e] * xw[(size_t)acol[e] * OUT_DIM + lane];
        atomicAdd(&out[(size_t)arow[e] * OUT_DIM + lane], m);
    }
}

__global__ __launch_bounds__(256) void relu_inplace(float* __restrict__ o, int n4) {
    float4* p = (float4*)o;
    int i = blockIdx.x * 256 + threadIdx.x;
    const int stride = gridDim.x * 256;
    for (; i < n4; i += stride) {
        float4 v = p[i];
        v.x = v.x > 0.f ? v.x : 0.f;
        v.y = v.y > 0.f ? v.y : 0.f;
        v.z = v.z > 0.f ? v.z : 0.f;
        v.w = v.w > 0.f ? v.w : 0.f;
        p[i] = v;
    }
}

static inline size_t align256(size_t x) { return (x + 255) & ~(size_t)255; }

extern "C" void kernel_launch(void* const* d_in, const int* in_sizes, int n_in,
                              void* d_out, int out_size, void* d_ws, size_t ws_size,
                              hipStream_t stream) {
    const float* x    = (const float*)d_in[0];
    const float* w    = (const float*)d_in[1];
    const int*   arow = (const int*)d_in[2];
    const int*   acol = (const int*)d_in[3];
    const float* aval = (const float*)d_in[4];
    float*       out  = (float*)d_out;

    const int N = in_sizes[0] / IN_DIM;   // 50000
    const int E = in_sizes[2];            // 800000
    const int nchunks = (N + 255) / 256;

    char* ws = (char*)d_ws;
    const size_t szXW  = align256((size_t)N * OUT_DIM * sizeof(float));
    const size_t szCur = align256((size_t)N * sizeof(int));

    float* xw  = (float*)ws;
    int*   cur = (int*)(ws + szXW);

    gemm_xw_mfma<<<(N + 63) / 64, 256, 0, stream>>>(x, w, xw, N);

    // --- tier 1: packed 4 B buckets (requires col < 65536) ---
    const size_t szPayB = (size_t)N * BUCKET * sizeof(unsigned);
    const size_t needB  = szXW + szCur + szPayB;

    // --- tier 2: CSR counting sort ---
    const size_t szOffs = align256((size_t)(N + 1) * sizeof(int));
    const size_t szB    = 1024;
    const size_t szPayC = (size_t)E * sizeof(float2);
    const size_t needC  = szXW + szOffs + szCur + szB + szPayC;

    if (ws_size >= needB && N <= 65536) {
        unsigned* payload = (unsigned*)(ws + szXW + szCur);
        hipMemsetAsync(cur, 0, (size_t)N * sizeof(int), stream);
        const int fill_blocks = (E / 4 + 255) / 256;
        fill_buckets<<<fill_blocks, 256, 0, stream>>>(arow, acol, aval, cur,
                                                      payload, E);
        pull_buckets<<<(N + 3) / 4, 256, 0, stream>>>(cur, payload, xw, out, N,
                                                      arow, acol, aval, E);
    } else if (ws_size >= needC && nchunks <= 256) {
        int*    offs    = (int*)(ws + szXW + szCur);
        int*    bsum    = (int*)(ws + szXW + szCur + szOffs);
        float2* payload = (float2*)(ws + szXW + szCur + szOffs + szB);
        hipMemsetAsync(cur, 0, (size_t)N * sizeof(int), stream);
        hist_rows<<<800, 256, 0, stream>>>(arow, cur, E);
        scan1<<<nchunks, 256, 0, stream>>>(cur, offs, bsum, N);
        scan2<<<1, 256, 0, stream>>>(bsum, nchunks);
        scan3<<<nchunks, 256, 0, stream>>>(offs, cur, bsum, N, E);
        fill_csr<<<800, 256, 0, stream>>>(arow, acol, aval, cur, payload, E);
        pull_csr<<<(N + 3) / 4, 256, 0, stream>>>(offs, payload, xw, out, N);
    } else {
        hipMemsetAsync(d_out, 0, (size_t)out_size * sizeof(float), stream);
        scatter_edges<<<4096, 256, 0, stream>>>(arow, acol, aval, xw, out, E);
        relu_inplace<<<2048, 256, 0, stream>>>(out, out_size / 4);
    }
}